// Round 1
// baseline (629.504 us; speedup 1.0000x reference)
//
#include <hip/hip_runtime.h>
#include <stdint.h>

// Problem constants (fixed by the reference):
//   x: (32, 256, 58, 58) f32 binary {0,1};  w: (256, 256, 3, 3) f32
//   out: (32, 256, 56, 56) f32 = alpha[o] * (2*S - 2304),  S = XNOR matches
// Identity used: S = 2304 - P, P = popcount(xbits ^ wbits) over (c,kh,kw)
//   out = fma(-2*alpha[o], P, 2304*alpha[o])

#define BATCH 32
#define C_IN 256
#define OCH 256
#define HIN 58
#define WIN2 58
#define HOUT 56
#define WOUT 56
#define TAPS 9
#define WWORDS 8            // 256 channels / 32 bits
#define KW 72               // TAPS * WWORDS
#define HWIN (HIN * WIN2)   // 3364
#define HWOUT (HOUT * WOUT) // 3136
#define NPOS (BATCH * HWIN) // 107648 input positions

// ---------------------------------------------------------------------------
// Kernel 1: bit-pack x along channels.
// Thread t -> (w, p): w = word index [0,8), p = (b,y,xx) position.
// Consecutive lanes = consecutive xx -> coalesced 4B reads per c-iteration.
// ---------------------------------------------------------------------------
__global__ __launch_bounds__(256) void pack_x_kernel(
    const float* __restrict__ x, uint32_t* __restrict__ xp)
{
    int t = blockIdx.x * 256 + threadIdx.x;      // 0 .. 861184-1 (exactly 3364 blocks)
    int w = t / NPOS;
    int p = t - w * NPOS;
    int b = p / HWIN;
    int r = p - b * HWIN;                        // y*58 + xx
    const float* xb = x + (size_t)b * C_IN * HWIN + r + (size_t)(w * 32) * HWIN;
    uint32_t mbits = 0u;
    #pragma unroll
    for (int j = 0; j < 32; ++j) {
        float v = xb[(size_t)j * HWIN];
        mbits |= (v > 0.5f ? 1u : 0u) << j;
    }
    xp[(size_t)p * WWORDS + w] = mbits;
}

// ---------------------------------------------------------------------------
// Kernel 2: pack weights + compute per-o scale/bias. One block per o.
// Thread c in [0,256): reads 9 taps, ballot-packs sign bits, LDS-reduces |w|.
// ---------------------------------------------------------------------------
__global__ __launch_bounds__(256) void pack_w_kernel(
    const float* __restrict__ wt, uint32_t* __restrict__ wp,
    float* __restrict__ sA, float* __restrict__ sB)
{
    int o = blockIdx.x;
    int c = threadIdx.x;
    const float* wb = wt + ((size_t)o * C_IN + c) * TAPS;
    float wv[TAPS];
    float s = 0.f;
    #pragma unroll
    for (int t = 0; t < TAPS; ++t) {
        wv[t] = wb[t];
        s += fabsf(wv[t]);
    }
    int wave = c >> 6, lane = c & 63;
    #pragma unroll
    for (int t = 0; t < TAPS; ++t) {
        unsigned long long m = __ballot(wv[t] >= 0.0f);  // bit i = lane i = channel wave*64+i
        if (lane == 0) {
            wp[(size_t)o * KW + t * WWORDS + wave * 2]     = (uint32_t)m;
            wp[(size_t)o * KW + t * WWORDS + wave * 2 + 1] = (uint32_t)(m >> 32);
        }
    }
    __shared__ float red[256];
    red[c] = s;
    __syncthreads();
    for (int off = 128; off > 0; off >>= 1) {
        if (c < off) red[c] += red[c + off];
        __syncthreads();
    }
    if (c == 0) {
        float alpha = red[0] / (float)(C_IN * HWIN);   // n = C*H*W (input size, per ref)
        sA[o] = -2.0f * alpha;
        sB[o] = (float)(C_IN * TAPS) * alpha;          // 2304 * alpha
    }
}

// ---------------------------------------------------------------------------
// Kernel 3: main XNOR-popcount conv.
// Thread = one output position (b,oy,ox); loops 64 output channels.
// x window (72 u32) lives in VGPRs; weight words are wave-uniform -> s_load.
// Stores for a fixed o are contiguous across lanes -> coalesced.
// ---------------------------------------------------------------------------
__global__ __launch_bounds__(256, 4) void xnor_main_kernel(
    const uint32_t* __restrict__ xp, const uint32_t* __restrict__ wp,
    const float* __restrict__ sA, const float* __restrict__ sB,
    float* __restrict__ out)
{
    int m = blockIdx.x * 256 + threadIdx.x;      // 0 .. 100351 (exactly 392 blocks)
    int b = m / HWOUT;
    int r = m - b * HWOUT;
    int oy = r / WOUT;
    int ox = r - oy * WOUT;
    int obase = blockIdx.y * 64;

    // Load the 9-tap, 8-word window into registers (18 x uint4, 16B-aligned).
    uint32_t xv[KW];
    #pragma unroll
    for (int dy = 0; dy < 3; ++dy) {
        #pragma unroll
        for (int dx = 0; dx < 3; ++dx) {
            const uint4* src = (const uint4*)(xp +
                (((size_t)b * HIN + (oy + dy)) * WIN2 + (ox + dx)) * WWORDS);
            uint4 a0 = src[0];
            uint4 a1 = src[1];
            int base = (dy * 3 + dx) * WWORDS;
            xv[base + 0] = a0.x; xv[base + 1] = a0.y;
            xv[base + 2] = a0.z; xv[base + 3] = a0.w;
            xv[base + 4] = a1.x; xv[base + 5] = a1.y;
            xv[base + 6] = a1.z; xv[base + 7] = a1.w;
        }
    }

    float* op = out + ((size_t)b * OCH + obase) * HWOUT + (size_t)oy * WOUT + ox;
    for (int oo = 0; oo < 64; ++oo) {
        int o = obase + oo;
        const uint32_t* wb = wp + (size_t)o * KW;    // uniform -> scalar loads
        int p0 = 0, p1 = 0, p2 = 0, p3 = 0;          // 4 chains to hide VALU latency
        #pragma unroll
        for (int i = 0; i < KW; i += 4) {
            p0 += __popc(wb[i + 0] ^ xv[i + 0]);
            p1 += __popc(wb[i + 1] ^ xv[i + 1]);
            p2 += __popc(wb[i + 2] ^ xv[i + 2]);
            p3 += __popc(wb[i + 3] ^ xv[i + 3]);
        }
        float P = (float)((p0 + p1) + (p2 + p3));
        op[(size_t)oo * HWOUT] = fmaf(sA[o], P, sB[o]);
    }
}

// ---------------------------------------------------------------------------
extern "C" void kernel_launch(void* const* d_in, const int* in_sizes, int n_in,
                              void* d_out, int out_size, void* d_ws, size_t ws_size,
                              hipStream_t stream)
{
    const float* x  = (const float*)d_in[0];
    const float* wt = (const float*)d_in[1];
    float* out = (float*)d_out;

    // Workspace layout (≈3.52 MB total):
    char* ws = (char*)d_ws;
    uint32_t* xp = (uint32_t*)ws;                               // 3,444,736 B
    uint32_t* wp = (uint32_t*)(ws + 3444736);                   //    73,728 B
    float*    sA = (float*)(ws + 3444736 + 73728);              //     1,024 B
    float*    sB = (float*)(ws + 3444736 + 73728 + 1024);       //     1,024 B

    // 1) pack x: 861,184 words / 256 = 3364 blocks exactly
    pack_x_kernel<<<dim3(3364), dim3(256), 0, stream>>>(x, xp);

    // 2) pack weights + scales: one block per output channel
    pack_w_kernel<<<dim3(OCH), dim3(256), 0, stream>>>(wt, wp, sA, sB);

    // 3) main: 100,352 positions / 256 = 392 blocks, 4 o-groups of 64
    xnor_main_kernel<<<dim3(392, 4), dim3(256), 0, stream>>>(xp, wp, sA, sB, out);
}

// Round 2
// 329.818 us; speedup vs baseline: 1.9086x; 1.9086x over previous
//
#include <hip/hip_runtime.h>
#include <stdint.h>

// Problem constants (fixed by the reference):
//   x: (32, 256, 58, 58) f32 binary {0,1};  w: (256, 256, 3, 3) f32
//   out: (32, 256, 56, 56) f32 = alpha[o] * (2*S - 2304),  S = XNOR matches
// Identity used: S = 2304 - P, P = popcount(xbits ^ wbits) over (c,kh,kw)
//   out = fma(-2*alpha[o], P, 2304*alpha[o])

#define BATCH 32
#define C_IN 256
#define OCH 256
#define HIN 58
#define WIN2 58
#define HOUT 56
#define WOUT 56
#define TAPS 9
#define WWORDS 8            // 256 channels / 32 bits
#define KW 72               // TAPS * WWORDS
#define HWIN (HIN * WIN2)   // 3364
#define HWOUT (HOUT * WOUT) // 3136
#define NPOS (BATCH * HWIN) // 107648 input positions

// ---------------------------------------------------------------------------
// Kernel 1: bit-pack x along channels.
// Thread t -> (w, p): w = word index [0,8), p = (b,y,xx) position.
// Consecutive lanes = consecutive xx -> coalesced 4B reads per c-iteration.
// ---------------------------------------------------------------------------
__global__ __launch_bounds__(256) void pack_x_kernel(
    const float* __restrict__ x, uint32_t* __restrict__ xp)
{
    int t = blockIdx.x * 256 + threadIdx.x;      // 0 .. 861184-1 (exactly 3364 blocks)
    int w = t / NPOS;
    int p = t - w * NPOS;
    int b = p / HWIN;
    int r = p - b * HWIN;                        // y*58 + xx
    const float* xb = x + (size_t)b * C_IN * HWIN + r + (size_t)(w * 32) * HWIN;
    uint32_t mbits = 0u;
    #pragma unroll
    for (int j = 0; j < 32; ++j) {
        float v = xb[(size_t)j * HWIN];
        mbits |= (v > 0.5f ? 1u : 0u) << j;
    }
    xp[(size_t)p * WWORDS + w] = mbits;
}

// ---------------------------------------------------------------------------
// Kernel 2: pack weights + compute per-o scale/bias. One block per o.
// Thread c in [0,256): reads 9 taps, ballot-packs sign bits, LDS-reduces |w|.
// ---------------------------------------------------------------------------
__global__ __launch_bounds__(256) void pack_w_kernel(
    const float* __restrict__ wt, uint32_t* __restrict__ wp,
    float* __restrict__ sA, float* __restrict__ sB)
{
    int o = blockIdx.x;
    int c = threadIdx.x;
    const float* wb = wt + ((size_t)o * C_IN + c) * TAPS;
    float wv[TAPS];
    float s = 0.f;
    #pragma unroll
    for (int t = 0; t < TAPS; ++t) {
        wv[t] = wb[t];
        s += fabsf(wv[t]);
    }
    int wave = c >> 6, lane = c & 63;
    #pragma unroll
    for (int t = 0; t < TAPS; ++t) {
        unsigned long long m = __ballot(wv[t] >= 0.0f);  // bit i = lane i = channel wave*64+i
        if (lane == 0) {
            wp[(size_t)o * KW + t * WWORDS + wave * 2]     = (uint32_t)m;
            wp[(size_t)o * KW + t * WWORDS + wave * 2 + 1] = (uint32_t)(m >> 32);
        }
    }
    __shared__ float red[256];
    red[c] = s;
    __syncthreads();
    for (int off = 128; off > 0; off >>= 1) {
        if (c < off) red[c] += red[c + off];
        __syncthreads();
    }
    if (c == 0) {
        float alpha = red[0] / (float)(C_IN * HWIN);   // n = C*H*W (input size, per ref)
        sA[o] = -2.0f * alpha;
        sB[o] = (float)(C_IN * TAPS) * alpha;          // 2304 * alpha
    }
}

// ---------------------------------------------------------------------------
// Kernel 3: main XNOR-popcount conv.
// Thread = one output position (b,oy,ox); loops 64 output channels.
// x window: 18 uint4 (72 words) held in VGPRs. launch_bounds(256,2) gives a
// 256-VGPR cap so the allocator does NOT spill the array (R1: cap 128 ->
// full spill to scratch -> 827 MB HBM fetch, kernel became HBM-bound).
// Weight words are wave-uniform -> scalar K$ loads (SGPRs, free of VALU).
// Stores for a fixed o are contiguous across lanes -> coalesced.
// ---------------------------------------------------------------------------
__global__ __launch_bounds__(256, 2) void xnor_main_kernel(
    const uint32_t* __restrict__ xp, const uint32_t* __restrict__ wp,
    const float* __restrict__ sA, const float* __restrict__ sB,
    float* __restrict__ out)
{
    int m = blockIdx.x * 256 + threadIdx.x;      // 0 .. 100351 (exactly 392 blocks)
    int b = m / HWOUT;
    int r = m - b * HWOUT;
    int oy = r / WOUT;
    int ox = r - oy * WOUT;
    int obase = blockIdx.y * 64;

    // Load the 9-tap, 8-word window straight into the register array.
    uint4 xv[2 * TAPS];
    #pragma unroll
    for (int dy = 0; dy < 3; ++dy) {
        #pragma unroll
        for (int dx = 0; dx < 3; ++dx) {
            const uint4* src = (const uint4*)(xp +
                (((size_t)b * HIN + (oy + dy)) * WIN2 + (ox + dx)) * WWORDS);
            xv[(dy * 3 + dx) * 2 + 0] = src[0];
            xv[(dy * 3 + dx) * 2 + 1] = src[1];
        }
    }

    float* op = out + ((size_t)b * OCH + obase) * HWOUT + (size_t)oy * WOUT + ox;
    for (int oo = 0; oo < 64; ++oo) {
        int o = obase + oo;
        const uint32_t* wb = wp + (size_t)o * KW;    // uniform -> scalar loads
        int p0 = 0, p1 = 0, p2 = 0, p3 = 0;          // 4 chains to hide VALU latency
        #pragma unroll
        for (int j = 0; j < 2 * TAPS; ++j) {
            p0 += __popc(wb[4 * j + 0] ^ xv[j].x);
            p1 += __popc(wb[4 * j + 1] ^ xv[j].y);
            p2 += __popc(wb[4 * j + 2] ^ xv[j].z);
            p3 += __popc(wb[4 * j + 3] ^ xv[j].w);
        }
        float P = (float)((p0 + p1) + (p2 + p3));
        op[(size_t)oo * HWOUT] = fmaf(sA[o], P, sB[o]);
    }
}

// ---------------------------------------------------------------------------
extern "C" void kernel_launch(void* const* d_in, const int* in_sizes, int n_in,
                              void* d_out, int out_size, void* d_ws, size_t ws_size,
                              hipStream_t stream)
{
    const float* x  = (const float*)d_in[0];
    const float* wt = (const float*)d_in[1];
    float* out = (float*)d_out;

    // Workspace layout (≈3.52 MB total):
    char* ws = (char*)d_ws;
    uint32_t* xp = (uint32_t*)ws;                               // 3,444,736 B
    uint32_t* wp = (uint32_t*)(ws + 3444736);                   //    73,728 B
    float*    sA = (float*)(ws + 3444736 + 73728);              //     1,024 B
    float*    sB = (float*)(ws + 3444736 + 73728 + 1024);       //     1,024 B

    // 1) pack x: 861,184 words / 256 = 3364 blocks exactly
    pack_x_kernel<<<dim3(3364), dim3(256), 0, stream>>>(x, xp);

    // 2) pack weights + scales: one block per output channel
    pack_w_kernel<<<dim3(OCH), dim3(256), 0, stream>>>(wt, wp, sA, sB);

    // 3) main: 100,352 positions / 256 = 392 blocks, 4 o-groups of 64
    xnor_main_kernel<<<dim3(392, 4), dim3(256), 0, stream>>>(xp, wp, sA, sB, out);
}